// Round 7
// baseline (3359.839 us; speedup 1.0000x reference)
//
#include <hip/hip_runtime.h>
#include <math.h>

#define S_LEN 2048
#define B_SZ 8
#define D_IN 1024
#define DS_ 128
#define INV_TEMP (1.0f/1.000001f)

// Relaxed workgroup barrier: orders LDS ops only (no vmcnt drain) — global
// prefetch loads stay in flight across it.
#define BAR_LDS() asm volatile("s_waitcnt lgkmcnt(0)\n\ts_barrier" ::: "memory")

// DPP row-butterfly sum across the 16-lane row (lanes sharing tid>>4).
#define DPPADD(x, ctrl) { int t_ = __builtin_amdgcn_update_dpp( \
    0, __float_as_int(x), ctrl, 0xF, 0xF, false); x += __int_as_float(t_); }
#define ROWSUM(x) { DPPADD(x, 0x128) DPPADD(x, 0x124) DPPADD(x, 0x122) DPPADD(x, 0x121) }
#define ROWSUM4(v4) { ROWSUM(v4.x) ROWSUM(v4.y) ROWSUM(v4.z) ROWSUM(v4.w) }

// Cross-row butterfly via gfx950 permlane swaps (VALU pipe). Subscript access
// only — macro args must not substitute into member names (round-3 lesson).
typedef unsigned int uint2v __attribute__((ext_vector_type(2)));
#define XSUM16(XV) { uint2v r_ = __builtin_amdgcn_permlane16_swap( \
    __float_as_uint(XV), __float_as_uint(XV), false, false); \
    XV = __uint_as_float(r_[0]) + __uint_as_float(r_[1]); }
#define XSUM32(XV) { uint2v r_ = __builtin_amdgcn_permlane32_swap( \
    __float_as_uint(XV), __float_as_uint(XV), false, false); \
    XV = __uint_as_float(r_[0]) + __uint_as_float(r_[1]); }

// ---------------------------------------------------------------------------
// Kernel 1: fused projection GEMM  P[16384][512] = x @ [Wk|Wv|Wq|Wa]^T
// 128x128 tile, 8x8 acc/thread. N-tile==128 => one W matrix per block.
// ---------------------------------------------------------------------------
__global__ __launch_bounds__(256) void proj_gemm(
    const float* __restrict__ X,
    const float* __restrict__ Wk, const float* __restrict__ Wv,
    const float* __restrict__ Wq, const float* __restrict__ Wa,
    float* __restrict__ P)
{
    __shared__ __align__(16) float As[32][132];
    __shared__ __align__(16) float Bs[32][132];
    const int tid = threadIdx.x;
    const int m0 = blockIdx.x * 128;
    const int n0 = blockIdx.y * 128;
    const int sr = tid >> 3;
    const int sk = tid & 7;
    const float* Wbase = (n0 == 0) ? Wk : (n0 == 128) ? Wv : (n0 == 256) ? Wq : Wa;
    const int ty = tid >> 4, tx = tid & 15;

    float acc[8][8];
#pragma unroll
    for (int i = 0; i < 8; i++)
#pragma unroll
        for (int j = 0; j < 8; j++) acc[i][j] = 0.f;

    for (int k0 = 0; k0 < D_IN; k0 += 32) {
#pragma unroll
        for (int i = 0; i < 4; i++) {
            int m = sr + i * 32;
            float4 a4 = *(const float4*)(X + (size_t)(m0 + m) * D_IN + k0 + sk * 4);
            As[sk*4+0][m] = a4.x; As[sk*4+1][m] = a4.y;
            As[sk*4+2][m] = a4.z; As[sk*4+3][m] = a4.w;
            float4 b4 = *(const float4*)(Wbase + (size_t)m * D_IN + k0 + sk * 4);
            Bs[sk*4+0][m] = b4.x; Bs[sk*4+1][m] = b4.y;
            Bs[sk*4+2][m] = b4.z; Bs[sk*4+3][m] = b4.w;
        }
        __syncthreads();
#pragma unroll
        for (int kk = 0; kk < 32; kk++) {
            float4 a0 = *(const float4*)(&As[kk][ty * 8]);
            float4 a1 = *(const float4*)(&As[kk][ty * 8 + 4]);
            float4 b0 = *(const float4*)(&Bs[kk][tx * 8]);
            float4 b1 = *(const float4*)(&Bs[kk][tx * 8 + 4]);
            float a[8] = {a0.x,a0.y,a0.z,a0.w,a1.x,a1.y,a1.z,a1.w};
            float b[8] = {b0.x,b0.y,b0.z,b0.w,b1.x,b1.y,b1.z,b1.w};
#pragma unroll
            for (int i = 0; i < 8; i++)
#pragma unroll
                for (int j = 0; j < 8; j++)
                    acc[i][j] = fmaf(a[i], b[j], acc[i][j]);
        }
        __syncthreads();
    }
#pragma unroll
    for (int i = 0; i < 8; i++) {
        float4 o0; o0.x = acc[i][0]; o0.y = acc[i][1]; o0.z = acc[i][2]; o0.w = acc[i][3];
        float4 o1; o1.x = acc[i][4]; o1.y = acc[i][5]; o1.z = acc[i][6]; o1.w = acc[i][7];
        float* dst = P + (size_t)(m0 + ty * 8 + i) * 512 + n0 + tx * 8;
        *(float4*)(dst) = o0; *(float4*)(dst + 4) = o1;
    }
}

// ---------------------------------------------------------------------------
// Kernel 2: postprocess per token. In-place on P: k<-l2norm(k), q<-l2norm(q),
// r-slot<-alpha. G[tok] = sum_k q_k*(1-alpha_k)*k_k.
// ---------------------------------------------------------------------------
__global__ __launch_bounds__(128) void postproc(
    float* __restrict__ P, float* __restrict__ G,
    const float* __restrict__ bA, const float* __restrict__ lam)
{
    const int tok = blockIdx.x, i = threadIdx.x;
    float* row = P + (size_t)tok * 512;
    float kr = row[i], qr = row[256 + i], rr = row[384 + i];
    float ks = kr * kr, qs = qr * qr;
#pragma unroll
    for (int m = 1; m < 64; m <<= 1) { ks += __shfl_xor(ks, m); qs += __shfl_xor(qs, m); }
    __shared__ float sb[6];
    if ((i & 63) == 0) { sb[(i >> 6) * 2] = ks; sb[(i >> 6) * 2 + 1] = qs; }
    __syncthreads();
    float kinv = 1.0f / fmaxf(sqrtf(sb[0] + sb[2]), 1e-12f);
    float qinv = 1.0f / fmaxf(sqrtf(sb[1] + sb[3]), 1e-12f);
    float kn = kr * kinv, qn = qr * qinv;
    float sr = 1.0f / (1.0f + __expf(-(rr + bA[i])));
    float sl = 1.0f / (1.0f + __expf(-lam[i]));
    float la = logf(sl + 1e-8f);
    float al = __expf(8.0f * sr * la);
    row[i] = kn; row[256 + i] = qn; row[384 + i] = al;
    float gi = qn * (1.0f - al) * kn;
#pragma unroll
    for (int m = 1; m < 64; m <<= 1) gi += __shfl_xor(gi, m);
    if ((i & 63) == 0) sb[4 + (i >> 6)] = gi;
    __syncthreads();
    if (i == 0) G[tok] = sb[4] + sb[5];
}

// ---------------------------------------------------------------------------
// Kernel 3: sequential recurrence — TWO-TOKEN FUSED steps (one barrier per 2
// tokens). R0-R5 established an invariant ~2730cyc/token floor dominated by
// the per-token sync tail (ep->barrier->sur->update), not by issue slots,
// LDS, or staging. H_t is linear in sur_t, so token t+1's err expands as
// err' = C0 - 2 sur C1 + sur^2 C2 with coefficients computable against
// H_{t-1} BEFORE the barrier; the single exchange carries 4 scalars/wave.
// Thread (c=tid&15, vp=tid>>4) owns H[k][v], k in [c*8,+8), v in [vp*4,+4).
// Register-direct staging (R5); LDS = 2x8 float4 exchange only.
// NOTE on macros: pasted names are parenthesized before member access,
// (k##S##0).x — "0.x" is a single pp-number token so k##S##0.x won't paste
// (round-6 compile failure).
// ---------------------------------------------------------------------------
__global__ __launch_bounds__(512, 2) void recurrence(
    const float* __restrict__ P, const float* __restrict__ G, float* __restrict__ Y)
{
    const int b = blockIdx.x;
    const int tid = threadIdx.x;
    const int c = tid & 15;
    const int vp = tid >> 4;      // 0..31
    const int wave = tid >> 6;    // 0..7
    const int ko = c * 8;         // k/q/a slice offset in P row
    const int vo = 128 + vp * 4;  // v slice offset in P row

    __shared__ __align__(16) float4 errw[2][8];

    const float* Pb = P + (size_t)b * S_LEN * 512;
    const float* Gb = G + (size_t)b * S_LEN;
    float* Yb = Y + (size_t)b * S_LEN * DS_;

    float4 H0={0,0,0,0},H1={0,0,0,0},H2={0,0,0,0},H3={0,0,0,0},
           H4={0,0,0,0},H5={0,0,0,0},H6={0,0,0,0},H7={0,0,0,0};

    // Two register sets (A,B); each holds TWO tokens: first token k/q/a/v,
    // second token j(=k') r(=q') bb(=alpha') u(=v').
    float4 kA0,kA1,qA0,qA1,aA0,aA1,vA, jA0,jA1,rA0,rA1,bbA0,bbA1,uA;
    float4 kB0,kB1,qB0,qB1,aB0,aB1,vB, jB0,jB1,rB0,rB1,bbB0,bbB1,uB;
    float gA,hA,gB,hB;

#define LOADP(S, T) { \
    const float* p0_ = Pb + (size_t)(T) * 512; \
    k##S##0 = *(const float4*)(p0_ + ko);       k##S##1 = *(const float4*)(p0_ + ko + 4); \
    q##S##0 = *(const float4*)(p0_ + 256 + ko); q##S##1 = *(const float4*)(p0_ + 256 + ko + 4); \
    a##S##0 = *(const float4*)(p0_ + 384 + ko); a##S##1 = *(const float4*)(p0_ + 384 + ko + 4); \
    v##S    = *(const float4*)(p0_ + vo); \
    const float* p1_ = p0_ + 512; \
    j##S##0 = *(const float4*)(p1_ + ko);        j##S##1 = *(const float4*)(p1_ + ko + 4); \
    r##S##0 = *(const float4*)(p1_ + 256 + ko);  r##S##1 = *(const float4*)(p1_ + 256 + ko + 4); \
    bb##S##0 = *(const float4*)(p1_ + 384 + ko); bb##S##1 = *(const float4*)(p1_ + 384 + ko + 4); \
    u##S    = *(const float4*)(p1_ + vo); }

    LOADP(A, 0) LOADP(B, 2)
    gA = Gb[0]; hA = Gb[1]; gB = Gb[2]; hB = Gb[3];

// FD: per-k-chunk element j. Accumulates the 6 H-dots and 3 k-scalars,
// stashes AW=(a' w), WY=w'=(1-a')k', AA=a a' for the post-barrier update.
#define FD(Hj, KX, QX, AX, KY, QY, AY, idx) { \
    const float wt_ = fmaf(-(KX), (AX), (KX)); \
    const float qy2_ = (QY) * (AY); \
    Sqw = fmaf((QY), wt_, Sqw); Skw = fmaf((KY), wt_, Skw); Sqaw = fmaf(qy2_, wt_, Sqaw); \
    AW[idx] = (AY) * wt_; WY[idx] = fmaf(-(KY), (AY), (KY)); AA[idx] = (AX) * (AY); \
    const float zt_ = (QX) * (AX); \
    const float qa_ = (QY) * (AX); \
    const float ka_ = (KY) * (AX); \
    const float za_ = qy2_ * (AX); \
    PR.x = fmaf((QX), Hj.x, PR.x); PR.y = fmaf((QX), Hj.y, PR.y); \
    PR.z = fmaf((QX), Hj.z, PR.z); PR.w = fmaf((QX), Hj.w, PR.w); \
    KP.x = fmaf((KX), Hj.x, KP.x); KP.y = fmaf((KX), Hj.y, KP.y); \
    KP.z = fmaf((KX), Hj.z, KP.z); KP.w = fmaf((KX), Hj.w, KP.w); \
    YA.x = fmaf(zt_, Hj.x, YA.x); YA.y = fmaf(zt_, Hj.y, YA.y); \
    YA.z = fmaf(zt_, Hj.z, YA.z); YA.w = fmaf(zt_, Hj.w, YA.w); \
    PA.x = fmaf(qa_, Hj.x, PA.x); PA.y = fmaf(qa_, Hj.y, PA.y); \
    PA.z = fmaf(qa_, Hj.z, PA.z); PA.w = fmaf(qa_, Hj.w, PA.w); \
    KA.x = fmaf(ka_, Hj.x, KA.x); KA.y = fmaf(ka_, Hj.y, KA.y); \
    KA.z = fmaf(ka_, Hj.z, KA.z); KA.w = fmaf(ka_, Hj.w, KA.w); \
    YB.x = fmaf(za_, Hj.x, YB.x); YB.y = fmaf(za_, Hj.y, YB.y); \
    YB.z = fmaf(za_, Hj.z, YB.z); YB.w = fmaf(za_, Hj.w, YB.w); }

#define HUPD(Hj, idx) { \
    const float u_ = sur * AW[idx]; const float u2_ = sur2 * WY[idx]; \
    const float aj_ = AA[idx]; \
    Hj.x = fmaf(aj_, Hj.x, fmaf(u2_, d2.x, u_ * dt.x)); \
    Hj.y = fmaf(aj_, Hj.y, fmaf(u2_, d2.y, u_ * dt.y)); \
    Hj.z = fmaf(aj_, Hj.z, fmaf(u2_, d2.z, u_ * dt.z)); \
    Hj.w = fmaf(aj_, Hj.w, fmaf(u2_, d2.w, u_ * dt.w)); }

#define FSTEP(T, PAR, S) { \
    float4 PR={0,0,0,0},KP={0,0,0,0},YA={0,0,0,0},PA={0,0,0,0},KA={0,0,0,0},YB={0,0,0,0}; \
    float Sqw=0.f, Skw=0.f, Sqaw=0.f; \
    float AW[8], WY[8], AA[8]; \
    FD(H0, (k##S##0).x, (q##S##0).x, (a##S##0).x, (j##S##0).x, (r##S##0).x, (bb##S##0).x, 0) \
    FD(H1, (k##S##0).y, (q##S##0).y, (a##S##0).y, (j##S##0).y, (r##S##0).y, (bb##S##0).y, 1) \
    FD(H2, (k##S##0).z, (q##S##0).z, (a##S##0).z, (j##S##0).z, (r##S##0).z, (bb##S##0).z, 2) \
    FD(H3, (k##S##0).w, (q##S##0).w, (a##S##0).w, (j##S##0).w, (r##S##0).w, (bb##S##0).w, 3) \
    FD(H4, (k##S##1).x, (q##S##1).x, (a##S##1).x, (j##S##1).x, (r##S##1).x, (bb##S##1).x, 4) \
    FD(H5, (k##S##1).y, (q##S##1).y, (a##S##1).y, (j##S##1).y, (r##S##1).y, (bb##S##1).y, 5) \
    FD(H6, (k##S##1).z, (q##S##1).z, (a##S##1).z, (j##S##1).z, (r##S##1).z, (bb##S##1).z, 6) \
    FD(H7, (k##S##1).w, (q##S##1).w, (a##S##1).w, (j##S##1).w, (r##S##1).w, (bb##S##1).w, 7) \
    ROWSUM4(PR) ROWSUM4(KP) ROWSUM4(YA) ROWSUM4(PA) ROWSUM4(KA) ROWSUM4(YB) \
    ROWSUM(Sqw) ROWSUM(Skw) ROWSUM(Sqaw) \
    float4 dt; dt.x = (v##S).x - KP.x; dt.y = (v##S).y - KP.y; \
    dt.z = (v##S).z - KP.z; dt.w = (v##S).w - KP.w; \
    float ex_ = (v##S).x - PR.x, ey_ = (v##S).y - PR.y, \
          ez_ = (v##S).z - PR.z, ew_ = (v##S).w - PR.w; \
    float ep = fmaf(ex_, ex_, fmaf(ey_, ey_, fmaf(ez_, ez_, ew_ * ew_))); \
    float4 ee; ee.x = (u##S).x - PA.x; ee.y = (u##S).y - PA.y; \
    ee.z = (u##S).z - PA.z; ee.w = (u##S).w - PA.w; \
    float4 e2; e2.x = (u##S).x - KA.x; e2.y = (u##S).y - KA.y; \
    e2.z = (u##S).z - KA.z; e2.w = (u##S).w - KA.w; \
    float4 Bv; Bv.x = Sqw * dt.x; Bv.y = Sqw * dt.y; \
    Bv.z = Sqw * dt.z; Bv.w = Sqw * dt.w; \
    float C0 = fmaf(ee.x, ee.x, fmaf(ee.y, ee.y, fmaf(ee.z, ee.z, ee.w * ee.w))); \
    float C1 = fmaf(ee.x, Bv.x, fmaf(ee.y, Bv.y, fmaf(ee.z, Bv.z, ee.w * Bv.w))); \
    float C2 = fmaf(Bv.x, Bv.x, fmaf(Bv.y, Bv.y, fmaf(Bv.z, Bv.z, Bv.w * Bv.w))); \
    XSUM16(ep) XSUM32(ep) XSUM16(C0) XSUM32(C0) \
    XSUM16(C1) XSUM32(C1) XSUM16(C2) XSUM32(C2) \
    if ((tid & 63) == 0) { \
        float4 pk_; pk_.x = ep; pk_.y = C0; pk_.z = C1; pk_.w = C2; \
        errw[(PAR)][wave] = pk_; } \
    if ((T) + 4 < S_LEN) LOADP(S, (T) + 4) \
    BAR_LDS(); \
    float4 E0 = errw[(PAR)][0], E1 = errw[(PAR)][1], E2 = errw[(PAR)][2], E3 = errw[(PAR)][3]; \
    float4 E4 = errw[(PAR)][4], E5 = errw[(PAR)][5], E6 = errw[(PAR)][6], E7 = errw[(PAR)][7]; \
    float sep = ((E0.x+E1.x)+(E2.x+E3.x))+((E4.x+E5.x)+(E6.x+E7.x)); \
    float sc0 = ((E0.y+E1.y)+(E2.y+E3.y))+((E4.y+E5.y)+(E6.y+E7.y)); \
    float sc1 = ((E0.z+E1.z)+(E2.z+E3.z))+((E4.z+E5.z)+(E6.z+E7.z)); \
    float sc2 = ((E0.w+E1.w)+(E2.w+E3.w))+((E4.w+E5.w)+(E6.w+E7.w)); \
    float sur = 1.0f / (1.0f + __expf(-sep * INV_TEMP)); \
    float errN = fmaf(sur, fmaf(sur, sc2, -2.0f * sc1), sc0); \
    float sur2 = 1.0f / (1.0f + __expf(-errN * INV_TEMP)); \
    const float gc1_ = g##S; const float gc2_ = h##S; \
    if ((T) + 4 < S_LEN) { g##S = Gb[(T) + 4]; h##S = Gb[(T) + 5]; } \
    float ssk_ = sur * Skw; \
    float4 d2; d2.x = fmaf(-ssk_, dt.x, e2.x); d2.y = fmaf(-ssk_, dt.y, e2.y); \
    d2.z = fmaf(-ssk_, dt.z, e2.z); d2.w = fmaf(-ssk_, dt.w, e2.w); \
    if (c == 0) { \
        float sg_ = sur * gc1_; float4 y1_; \
        y1_.x = fmaf(sg_, dt.x, YA.x); y1_.y = fmaf(sg_, dt.y, YA.y); \
        y1_.z = fmaf(sg_, dt.z, YA.z); y1_.w = fmaf(sg_, dt.w, YA.w); \
        *(float4*)(Yb + (size_t)(T) * DS_ + vp * 4) = y1_; \
        float sq_ = sur * Sqaw; float sh_ = sur2 * gc2_; float4 y2_; \
        y2_.x = fmaf(sh_, d2.x, fmaf(sq_, dt.x, YB.x)); \
        y2_.y = fmaf(sh_, d2.y, fmaf(sq_, dt.y, YB.y)); \
        y2_.z = fmaf(sh_, d2.z, fmaf(sq_, dt.z, YB.z)); \
        y2_.w = fmaf(sh_, d2.w, fmaf(sq_, dt.w, YB.w)); \
        *(float4*)(Yb + (size_t)((T) + 1) * DS_ + vp * 4) = y2_; } \
    HUPD(H0, 0) HUPD(H1, 1) HUPD(H2, 2) HUPD(H3, 3) \
    HUPD(H4, 4) HUPD(H5, 5) HUPD(H6, 6) HUPD(H7, 7) \
}

    for (int t = 0; t < S_LEN; t += 4) {
        FSTEP(t,     0, A)
        FSTEP(t + 2, 1, B)
    }
#undef FSTEP
#undef HUPD
#undef FD
#undef LOADP
}

// ---------------------------------------------------------------------------
// Kernel 4: RMSNorm over DS per token (in-place on Y)
// ---------------------------------------------------------------------------
__global__ __launch_bounds__(128) void rmsnorm(
    float* __restrict__ Y, const float* __restrict__ nw)
{
    const int tok = blockIdx.x, i = threadIdx.x;
    float y = Y[(size_t)tok * DS_ + i];
    float s = y * y;
#pragma unroll
    for (int m = 1; m < 64; m <<= 1) s += __shfl_xor(s, m);
    __shared__ float sb[2];
    if ((i & 63) == 0) sb[i >> 6] = s;
    __syncthreads();
    float ms = (sb[0] + sb[1]) * (1.0f / 128.0f);
    Y[(size_t)tok * DS_ + i] = y * rsqrtf(ms + 1e-6f) * nw[i];
}

// ---------------------------------------------------------------------------
// Kernel 5: output GEMM  Out[16384][1024] = Yn[16384][128] @ Wo[1024][128]^T
// 128x128 tile, 8x8 acc/thread.
// ---------------------------------------------------------------------------
__global__ __launch_bounds__(256) void out_gemm(
    const float* __restrict__ Yn, const float* __restrict__ Wo, float* __restrict__ Out)
{
    __shared__ __align__(16) float As[32][132];
    __shared__ __align__(16) float Bs[32][132];
    const int tid = threadIdx.x;
    const int m0 = blockIdx.x * 128;
    const int n0 = blockIdx.y * 128;
    const int sr = tid >> 3;
    const int sk = tid & 7;
    const int ty = tid >> 4, tx = tid & 15;

    float acc[8][8];
#pragma unroll
    for (int i = 0; i < 8; i++)
#pragma unroll
        for (int j = 0; j < 8; j++) acc[i][j] = 0.f;

    for (int k0 = 0; k0 < DS_; k0 += 32) {
#pragma unroll
        for (int i = 0; i < 4; i++) {
            int m = sr + i * 32;
            float4 a4 = *(const float4*)(Yn + (size_t)(m0 + m) * DS_ + k0 + sk * 4);
            As[sk*4+0][m] = a4.x; As[sk*4+1][m] = a4.y;
            As[sk*4+2][m] = a4.z; As[sk*4+3][m] = a4.w;
            float4 b4 = *(const float4*)(Wo + (size_t)(n0 + m) * DS_ + k0 + sk * 4);
            Bs[sk*4+0][m] = b4.x; Bs[sk*4+1][m] = b4.y;
            Bs[sk*4+2][m] = b4.z; Bs[sk*4+3][m] = b4.w;
        }
        __syncthreads();
#pragma unroll
        for (int kk = 0; kk < 32; kk++) {
            float4 a0 = *(const float4*)(&As[kk][ty * 8]);
            float4 a1 = *(const float4*)(&As[kk][ty * 8 + 4]);
            float4 b0 = *(const float4*)(&Bs[kk][tx * 8]);
            float4 b1 = *(const float4*)(&Bs[kk][tx * 8 + 4]);
            float a[8] = {a0.x,a0.y,a0.z,a0.w,a1.x,a1.y,a1.z,a1.w};
            float b[8] = {b0.x,b0.y,b0.z,b0.w,b1.x,b1.y,b1.z,b1.w};
#pragma unroll
            for (int i = 0; i < 8; i++)
#pragma unroll
                for (int j = 0; j < 8; j++)
                    acc[i][j] = fmaf(a[i], b[j], acc[i][j]);
        }
        __syncthreads();
    }
#pragma unroll
    for (int i = 0; i < 8; i++) {
        float4 o0; o0.x = acc[i][0]; o0.y = acc[i][1]; o0.z = acc[i][2]; o0.w = acc[i][3];
        float4 o1; o1.x = acc[i][4]; o1.y = acc[i][5]; o1.z = acc[i][6]; o1.w = acc[i][7];
        float* dst = Out + (size_t)(m0 + ty * 8 + i) * 1024 + n0 + tx * 8;
        *(float4*)(dst) = o0; *(float4*)(dst + 4) = o1;
    }
}

// ---------------------------------------------------------------------------
extern "C" void kernel_launch(void* const* d_in, const int* in_sizes, int n_in,
                              void* d_out, int out_size, void* d_ws, size_t ws_size,
                              hipStream_t stream)
{
    const float* x   = (const float*)d_in[0];
    const float* Wk  = (const float*)d_in[1];
    const float* Wv  = (const float*)d_in[2];
    const float* Wq  = (const float*)d_in[3];
    const float* Waw = (const float*)d_in[4];
    const float* Wab = (const float*)d_in[5];
    const float* lam = (const float*)d_in[6];
    const float* Wo  = (const float*)d_in[7];
    const float* nw  = (const float*)d_in[8];
    float* out = (float*)d_out;

    const size_t NTOK = (size_t)B_SZ * S_LEN;   // 16384
    float* P  = (float*)d_ws;                    // NTOK*512
    float* G  = P + NTOK * 512;                  // NTOK
    float* Y  = G + NTOK;                        // NTOK*128

    proj_gemm<<<dim3(NTOK / 128, 512 / 128), 256, 0, stream>>>(x, Wk, Wv, Wq, Waw, P);
    postproc<<<NTOK, 128, 0, stream>>>(P, G, Wab, lam);
    recurrence<<<B_SZ, 512, 0, stream>>>(P, G, Y);
    rmsnorm<<<NTOK, 128, 0, stream>>>(Y, nw);
    out_gemm<<<dim3(NTOK / 128, 1024 / 128), 256, 0, stream>>>(Y, Wo, out);
}

// Round 8
// 2712.577 us; speedup vs baseline: 1.2386x; 1.2386x over previous
//
#include <hip/hip_runtime.h>
#include <math.h>

#define S_LEN 2048
#define B_SZ 8
#define D_IN 1024
#define DS_ 128
#define INV_TEMP (1.0f/1.000001f)

// Relaxed workgroup barrier: orders LDS ops only (no vmcnt drain) — global
// prefetch loads stay in flight across it.
#define BAR_LDS() asm volatile("s_waitcnt lgkmcnt(0)\n\ts_barrier" ::: "memory")

// DPP row-butterfly sum across the 16-lane row (lanes sharing tid>>4).
#define DPPADD(x, ctrl) { int t_ = __builtin_amdgcn_update_dpp( \
    0, __float_as_int(x), ctrl, 0xF, 0xF, false); x += __int_as_float(t_); }
#define ROWSUM(x) { DPPADD(x, 0x128) DPPADD(x, 0x124) DPPADD(x, 0x122) DPPADD(x, 0x121) }
#define ROWSUM4(v4) { ROWSUM(v4.x) ROWSUM(v4.y) ROWSUM(v4.z) ROWSUM(v4.w) }

// Cross-row butterfly via gfx950 permlane swaps (VALU pipe). Subscript access
// only — macro args must not substitute into member names (round-3 lesson).
typedef unsigned int uint2v __attribute__((ext_vector_type(2)));
#define XSUM16(XV) { uint2v r_ = __builtin_amdgcn_permlane16_swap( \
    __float_as_uint(XV), __float_as_uint(XV), false, false); \
    XV = __uint_as_float(r_[0]) + __uint_as_float(r_[1]); }
#define XSUM32(XV) { uint2v r_ = __builtin_amdgcn_permlane32_swap( \
    __float_as_uint(XV), __float_as_uint(XV), false, false); \
    XV = __uint_as_float(r_[0]) + __uint_as_float(r_[1]); }

// ---------------------------------------------------------------------------
// Kernel 1: fused projection GEMM  P[16384][512] = x @ [Wk|Wv|Wq|Wa]^T
// 128x128 tile, 8x8 acc/thread. N-tile==128 => one W matrix per block.
// ---------------------------------------------------------------------------
__global__ __launch_bounds__(256) void proj_gemm(
    const float* __restrict__ X,
    const float* __restrict__ Wk, const float* __restrict__ Wv,
    const float* __restrict__ Wq, const float* __restrict__ Wa,
    float* __restrict__ P)
{
    __shared__ __align__(16) float As[32][132];
    __shared__ __align__(16) float Bs[32][132];
    const int tid = threadIdx.x;
    const int m0 = blockIdx.x * 128;
    const int n0 = blockIdx.y * 128;
    const int sr = tid >> 3;
    const int sk = tid & 7;
    const float* Wbase = (n0 == 0) ? Wk : (n0 == 128) ? Wv : (n0 == 256) ? Wq : Wa;
    const int ty = tid >> 4, tx = tid & 15;

    float acc[8][8];
#pragma unroll
    for (int i = 0; i < 8; i++)
#pragma unroll
        for (int j = 0; j < 8; j++) acc[i][j] = 0.f;

    for (int k0 = 0; k0 < D_IN; k0 += 32) {
#pragma unroll
        for (int i = 0; i < 4; i++) {
            int m = sr + i * 32;
            float4 a4 = *(const float4*)(X + (size_t)(m0 + m) * D_IN + k0 + sk * 4);
            As[sk*4+0][m] = a4.x; As[sk*4+1][m] = a4.y;
            As[sk*4+2][m] = a4.z; As[sk*4+3][m] = a4.w;
            float4 b4 = *(const float4*)(Wbase + (size_t)m * D_IN + k0 + sk * 4);
            Bs[sk*4+0][m] = b4.x; Bs[sk*4+1][m] = b4.y;
            Bs[sk*4+2][m] = b4.z; Bs[sk*4+3][m] = b4.w;
        }
        __syncthreads();
#pragma unroll
        for (int kk = 0; kk < 32; kk++) {
            float4 a0 = *(const float4*)(&As[kk][ty * 8]);
            float4 a1 = *(const float4*)(&As[kk][ty * 8 + 4]);
            float4 b0 = *(const float4*)(&Bs[kk][tx * 8]);
            float4 b1 = *(const float4*)(&Bs[kk][tx * 8 + 4]);
            float a[8] = {a0.x,a0.y,a0.z,a0.w,a1.x,a1.y,a1.z,a1.w};
            float b[8] = {b0.x,b0.y,b0.z,b0.w,b1.x,b1.y,b1.z,b1.w};
#pragma unroll
            for (int i = 0; i < 8; i++)
#pragma unroll
                for (int j = 0; j < 8; j++)
                    acc[i][j] = fmaf(a[i], b[j], acc[i][j]);
        }
        __syncthreads();
    }
#pragma unroll
    for (int i = 0; i < 8; i++) {
        float4 o0; o0.x = acc[i][0]; o0.y = acc[i][1]; o0.z = acc[i][2]; o0.w = acc[i][3];
        float4 o1; o1.x = acc[i][4]; o1.y = acc[i][5]; o1.z = acc[i][6]; o1.w = acc[i][7];
        float* dst = P + (size_t)(m0 + ty * 8 + i) * 512 + n0 + tx * 8;
        *(float4*)(dst) = o0; *(float4*)(dst + 4) = o1;
    }
}

// ---------------------------------------------------------------------------
// Kernel 2: postprocess per token. In-place on P: k<-l2norm(k), q<-l2norm(q),
// r-slot<-alpha. G[tok] = sum_k q_k*(1-alpha_k)*k_k.
// ---------------------------------------------------------------------------
__global__ __launch_bounds__(128) void postproc(
    float* __restrict__ P, float* __restrict__ G,
    const float* __restrict__ bA, const float* __restrict__ lam)
{
    const int tok = blockIdx.x, i = threadIdx.x;
    float* row = P + (size_t)tok * 512;
    float kr = row[i], qr = row[256 + i], rr = row[384 + i];
    float ks = kr * kr, qs = qr * qr;
#pragma unroll
    for (int m = 1; m < 64; m <<= 1) { ks += __shfl_xor(ks, m); qs += __shfl_xor(qs, m); }
    __shared__ float sb[6];
    if ((i & 63) == 0) { sb[(i >> 6) * 2] = ks; sb[(i >> 6) * 2 + 1] = qs; }
    __syncthreads();
    float kinv = 1.0f / fmaxf(sqrtf(sb[0] + sb[2]), 1e-12f);
    float qinv = 1.0f / fmaxf(sqrtf(sb[1] + sb[3]), 1e-12f);
    float kn = kr * kinv, qn = qr * qinv;
    float sr = 1.0f / (1.0f + __expf(-(rr + bA[i])));
    float sl = 1.0f / (1.0f + __expf(-lam[i]));
    float la = logf(sl + 1e-8f);
    float al = __expf(8.0f * sr * la);
    row[i] = kn; row[256 + i] = qn; row[384 + i] = al;
    float gi = qn * (1.0f - al) * kn;
#pragma unroll
    for (int m = 1; m < 64; m <<= 1) gi += __shfl_xor(gi, m);
    if ((i & 63) == 0) sb[4 + (i >> 6)] = gi;
    __syncthreads();
    if (i == 0) G[tok] = sb[4] + sb[5];
}

// ---------------------------------------------------------------------------
// Kernel 3: sequential recurrence — R5 register-direct structure, issue-trimmed.
// Model from R0-R7: VALU-issue-bound at ~77%; time tracks instr count.
// Trims: (1) pointer-chain addressing — 6 k/q/a loads share one per-thread
// base + imm offsets (<=1552B), v on a second chain; chains advance by a
// single += 1024. (2) split update: dots pr/kp on H, then H*=a (pre-barrier),
// ya-dot on scaled H (z-prep gone), post-barrier UPDJ = 1 fma/elem.
// (3) epilogue peel: no per-step bounds branches in the main loop.
// Thread (c=tid&15, vp=tid>>4) owns H[k][v], k in [c*8,+8), v in [vp*4,+4).
// ---------------------------------------------------------------------------
__global__ __launch_bounds__(512, 2) void recurrence(
    const float* __restrict__ P, const float* __restrict__ G, float* __restrict__ Y)
{
    const int b = blockIdx.x;
    const int tid = threadIdx.x;
    const int c = tid & 15;
    const int vp = tid >> 4;      // 0..31
    const int wave = tid >> 6;    // 0..7
    const int ko = c * 8;
    const int vo = 128 + vp * 4;

    __shared__ __align__(16) float errw[2][8];

    const float* Pb = P + (size_t)b * S_LEN * 512;
    const float* Gb = G + (size_t)b * S_LEN;
    float* Yb = Y + (size_t)b * S_LEN * DS_;

    float4 H0={0,0,0,0},H1={0,0,0,0},H2={0,0,0,0},H3={0,0,0,0},
           H4={0,0,0,0},H5={0,0,0,0},H6={0,0,0,0},H7={0,0,0,0};

    // Two register sets (A = even tokens, B = odd), each with its own
    // pointer chains (pk: k/q/a block, pv: v block).
    float4 kA0,kA1,qA0,qA1,aA0,aA1,vA;
    float4 kB0,kB1,qB0,qB1,aB0,aB1,vB;
    float gA, gB;
    const float* pkA = Pb + ko;
    const float* pvA = Pb + vo;
    const float* pkB = Pb + 512 + ko;
    const float* pvB = Pb + 512 + vo;

    kA0 = *(const float4*)(pkA);       kA1 = *(const float4*)(pkA + 4);
    qA0 = *(const float4*)(pkA + 256); qA1 = *(const float4*)(pkA + 260);
    aA0 = *(const float4*)(pkA + 384); aA1 = *(const float4*)(pkA + 388);
    vA  = *(const float4*)(pvA);
    pkA += 1024; pvA += 1024;
    kB0 = *(const float4*)(pkB);       kB1 = *(const float4*)(pkB + 4);
    qB0 = *(const float4*)(pkB + 256); qB1 = *(const float4*)(pkB + 260);
    aB0 = *(const float4*)(pkB + 384); aB1 = *(const float4*)(pkB + 388);
    vB  = *(const float4*)(pvB);
    pkB += 1024; pvB += 1024;
    gA = Gb[0]; gB = Gb[1];

// pr += qs*Hj, kp += ks*Hj  (dots on UNSCALED H)
#define DOT2(qs, ks, Hj) { \
    pr.x = fmaf(qs, Hj.x, pr.x); pr.y = fmaf(qs, Hj.y, pr.y); \
    pr.z = fmaf(qs, Hj.z, pr.z); pr.w = fmaf(qs, Hj.w, pr.w); \
    kp.x = fmaf(ks, Hj.x, kp.x); kp.y = fmaf(ks, Hj.y, kp.y); \
    kp.z = fmaf(ks, Hj.z, kp.z); kp.w = fmaf(ks, Hj.w, kp.w); }

// scale Hj by scalar as_, then accumulate ya += qs*Hj (scaled)
#define SCYA(qs, as_, Hj) { \
    Hj.x *= as_; Hj.y *= as_; Hj.z *= as_; Hj.w *= as_; \
    ya.x = fmaf(qs, Hj.x, ya.x); ya.y = fmaf(qs, Hj.y, ya.y); \
    ya.z = fmaf(qs, Hj.z, ya.z); ya.w = fmaf(qs, Hj.w, ya.w); }

// post-barrier: Hj += w_j * sd  (1 fma/elem)
#define UPD1(ws_, Hj) { \
    Hj.x = fmaf(ws_, sd.x, Hj.x); Hj.y = fmaf(ws_, sd.y, Hj.y); \
    Hj.z = fmaf(ws_, sd.z, Hj.z); Hj.w = fmaf(ws_, sd.w, Hj.w); }

#define STEP(T, PAR, K0,K1,Q0,Q1,A0,A1,VT,GS,PK,PV, DOLD) { \
    float4 pr = {0,0,0,0}, kp = {0,0,0,0}; \
    DOT2(Q0.x, K0.x, H0) DOT2(Q0.y, K0.y, H1) \
    DOT2(Q0.z, K0.z, H2) DOT2(Q0.w, K0.w, H3) \
    DOT2(Q1.x, K1.x, H4) DOT2(Q1.y, K1.y, H5) \
    DOT2(Q1.z, K1.z, H6) DOT2(Q1.w, K1.w, H7) \
    float4 w0_, w1_; \
    w0_.x = fmaf(-K0.x, A0.x, K0.x); w0_.y = fmaf(-K0.y, A0.y, K0.y); \
    w0_.z = fmaf(-K0.z, A0.z, K0.z); w0_.w = fmaf(-K0.w, A0.w, K0.w); \
    w1_.x = fmaf(-K1.x, A1.x, K1.x); w1_.y = fmaf(-K1.y, A1.y, K1.y); \
    w1_.z = fmaf(-K1.z, A1.z, K1.z); w1_.w = fmaf(-K1.w, A1.w, K1.w); \
    float4 ya = {0,0,0,0}; \
    SCYA(Q0.x, A0.x, H0) SCYA(Q0.y, A0.y, H1) \
    SCYA(Q0.z, A0.z, H2) SCYA(Q0.w, A0.w, H3) \
    SCYA(Q1.x, A1.x, H4) SCYA(Q1.y, A1.y, H5) \
    SCYA(Q1.z, A1.z, H6) SCYA(Q1.w, A1.w, H7) \
    ROWSUM4(pr) ROWSUM4(kp) ROWSUM4(ya) \
    float4 d4; d4.x = VT.x - kp.x; d4.y = VT.y - kp.y; \
    d4.z = VT.z - kp.z; d4.w = VT.w - kp.w; \
    float ex_ = VT.x - pr.x, ey_ = VT.y - pr.y, \
          ez_ = VT.z - pr.z, ew_ = VT.w - pr.w; \
    float ep = fmaf(ex_, ex_, fmaf(ey_, ey_, fmaf(ez_, ez_, ew_ * ew_))); \
    XSUM16(ep) XSUM32(ep) \
    if ((tid & 63) == 0) errw[PAR][wave] = ep; \
    const float gcur = GS; \
    if (DOLD) { \
        K0 = *(const float4*)(PK);       K1 = *(const float4*)(PK + 4); \
        Q0 = *(const float4*)(PK + 256); Q1 = *(const float4*)(PK + 260); \
        A0 = *(const float4*)(PK + 384); A1 = *(const float4*)(PK + 388); \
        VT = *(const float4*)(PV); \
        PK += 1024; PV += 1024; } \
    BAR_LDS(); \
    const float4 ea = *(const float4*)(&errw[PAR][0]); \
    const float4 eb = *(const float4*)(&errw[PAR][4]); \
    float err = ((ea.x + ea.y) + (ea.z + ea.w)) + ((eb.x + eb.y) + (eb.z + eb.w)); \
    float sur = 1.0f / (1.0f + __expf(-err * INV_TEMP)); \
    if (DOLD) GS = Gb[(T) + 2]; \
    float4 sd; sd.x = sur * d4.x; sd.y = sur * d4.y; \
    sd.z = sur * d4.z; sd.w = sur * d4.w; \
    if (c == 0) { \
        float sg = sur * gcur; float4 y4; \
        y4.x = fmaf(sg, d4.x, ya.x); y4.y = fmaf(sg, d4.y, ya.y); \
        y4.z = fmaf(sg, d4.z, ya.z); y4.w = fmaf(sg, d4.w, ya.w); \
        *(float4*)(Yb + (size_t)(T) * DS_ + vp * 4) = y4; } \
    UPD1(w0_.x, H0) UPD1(w0_.y, H1) UPD1(w0_.z, H2) UPD1(w0_.w, H3) \
    UPD1(w1_.x, H4) UPD1(w1_.y, H5) UPD1(w1_.z, H6) UPD1(w1_.w, H7) \
}

    for (int t = 0; t < S_LEN - 2; t += 2) {
        STEP(t,     0, kA0,kA1,qA0,qA1,aA0,aA1,vA,gA,pkA,pvA, 1)
        STEP(t + 1, 1, kB0,kB1,qB0,qB1,aB0,aB1,vB,gB,pkB,pvB, 1)
    }
    STEP(S_LEN - 2, 0, kA0,kA1,qA0,qA1,aA0,aA1,vA,gA,pkA,pvA, 0)
    STEP(S_LEN - 1, 1, kB0,kB1,qB0,qB1,aB0,aB1,vB,gB,pkB,pvB, 0)
#undef STEP
#undef UPD1
#undef SCYA
#undef DOT2
}

// ---------------------------------------------------------------------------
// Kernel 4: RMSNorm over DS per token (in-place on Y)
// ---------------------------------------------------------------------------
__global__ __launch_bounds__(128) void rmsnorm(
    float* __restrict__ Y, const float* __restrict__ nw)
{
    const int tok = blockIdx.x, i = threadIdx.x;
    float y = Y[(size_t)tok * DS_ + i];
    float s = y * y;
#pragma unroll
    for (int m = 1; m < 64; m <<= 1) s += __shfl_xor(s, m);
    __shared__ float sb[2];
    if ((i & 63) == 0) sb[i >> 6] = s;
    __syncthreads();
    float ms = (sb[0] + sb[1]) * (1.0f / 128.0f);
    Y[(size_t)tok * DS_ + i] = y * rsqrtf(ms + 1e-6f) * nw[i];
}

// ---------------------------------------------------------------------------
// Kernel 5: output GEMM  Out[16384][1024] = Yn[16384][128] @ Wo[1024][128]^T
// 128x128 tile, 8x8 acc/thread.
// ---------------------------------------------------------------------------
__global__ __launch_bounds__(256) void out_gemm(
    const float* __restrict__ Yn, const float* __restrict__ Wo, float* __restrict__ Out)
{
    __shared__ __align__(16) float As[32][132];
    __shared__ __align__(16) float Bs[32][132];
    const int tid = threadIdx.x;
    const int m0 = blockIdx.x * 128;
    const int n0 = blockIdx.y * 128;
    const int sr = tid >> 3;
    const int sk = tid & 7;
    const int ty = tid >> 4, tx = tid & 15;

    float acc[8][8];
#pragma unroll
    for (int i = 0; i < 8; i++)
#pragma unroll
        for (int j = 0; j < 8; j++) acc[i][j] = 0.f;

    for (int k0 = 0; k0 < DS_; k0 += 32) {
#pragma unroll
        for (int i = 0; i < 4; i++) {
            int m = sr + i * 32;
            float4 a4 = *(const float4*)(Yn + (size_t)(m0 + m) * DS_ + k0 + sk * 4);
            As[sk*4+0][m] = a4.x; As[sk*4+1][m] = a4.y;
            As[sk*4+2][m] = a4.z; As[sk*4+3][m] = a4.w;
            float4 b4 = *(const float4*)(Wo + (size_t)(n0 + m) * DS_ + k0 + sk * 4);
            Bs[sk*4+0][m] = b4.x; Bs[sk*4+1][m] = b4.y;
            Bs[sk*4+2][m] = b4.z; Bs[sk*4+3][m] = b4.w;
        }
        __syncthreads();
#pragma unroll
        for (int kk = 0; kk < 32; kk++) {
            float4 a0 = *(const float4*)(&As[kk][ty * 8]);
            float4 a1 = *(const float4*)(&As[kk][ty * 8 + 4]);
            float4 b0 = *(const float4*)(&Bs[kk][tx * 8]);
            float4 b1 = *(const float4*)(&Bs[kk][tx * 8 + 4]);
            float a[8] = {a0.x,a0.y,a0.z,a0.w,a1.x,a1.y,a1.z,a1.w};
            float b[8] = {b0.x,b0.y,b0.z,b0.w,b1.x,b1.y,b1.z,b1.w};
#pragma unroll
            for (int i = 0; i < 8; i++)
#pragma unroll
                for (int j = 0; j < 8; j++)
                    acc[i][j] = fmaf(a[i], b[j], acc[i][j]);
        }
        __syncthreads();
    }
#pragma unroll
    for (int i = 0; i < 8; i++) {
        float4 o0; o0.x = acc[i][0]; o0.y = acc[i][1]; o0.z = acc[i][2]; o0.w = acc[i][3];
        float4 o1; o1.x = acc[i][4]; o1.y = acc[i][5]; o1.z = acc[i][6]; o1.w = acc[i][7];
        float* dst = Out + (size_t)(m0 + ty * 8 + i) * 1024 + n0 + tx * 8;
        *(float4*)(dst) = o0; *(float4*)(dst + 4) = o1;
    }
}

// ---------------------------------------------------------------------------
extern "C" void kernel_launch(void* const* d_in, const int* in_sizes, int n_in,
                              void* d_out, int out_size, void* d_ws, size_t ws_size,
                              hipStream_t stream)
{
    const float* x   = (const float*)d_in[0];
    const float* Wk  = (const float*)d_in[1];
    const float* Wv  = (const float*)d_in[2];
    const float* Wq  = (const float*)d_in[3];
    const float* Waw = (const float*)d_in[4];
    const float* Wab = (const float*)d_in[5];
    const float* lam = (const float*)d_in[6];
    const float* Wo  = (const float*)d_in[7];
    const float* nw  = (const float*)d_in[8];
    float* out = (float*)d_out;

    const size_t NTOK = (size_t)B_SZ * S_LEN;   // 16384
    float* P  = (float*)d_ws;                    // NTOK*512
    float* G  = P + NTOK * 512;                  // NTOK
    float* Y  = G + NTOK;                        // NTOK*128

    proj_gemm<<<dim3(NTOK / 128, 512 / 128), 256, 0, stream>>>(x, Wk, Wv, Wq, Waw, P);
    postproc<<<NTOK, 128, 0, stream>>>(P, G, Wab, lam);
    recurrence<<<B_SZ, 512, 0, stream>>>(P, G, Y);
    rmsnorm<<<NTOK, 128, 0, stream>>>(Y, nw);
    out_gemm<<<dim3(NTOK / 128, 1024 / 128), 256, 0, stream>>>(Y, Wo, out);
}